// Round 7
// baseline (81.308 us; speedup 1.0000x reference)
//
#include <hip/hip_runtime.h>
#include <math.h>

#define B_SZ 16384
#define D_DIM 128
#define A_SZ 8192
#define K_SZ 64
#define L2_REG_F 0.25f
#define CONV_BLK 2048  // convert kernel blocks (x4 waves -> 2 rows/wave)
#define NBLK 2048      // main kernel blocks: 1 wave per anchor

typedef float vfloat2 __attribute__((ext_vector_type(2)));

__device__ __forceinline__ float wave_reduce_sum(float v) {
    #pragma unroll
    for (int off = 32; off > 0; off >>= 1)
        v += __shfl_xor(v, off, 64);
    return v;
}

__device__ __forceinline__ float wave_reduce_max(float v) {
    #pragma unroll
    for (int off = 32; off > 0; off >>= 1)
        v = fmaxf(v, __shfl_xor(v, off, 64));
    return v;
}

// dequant 8 fp8 bytes (uint2-worth handled as two uints) -> 16 floats via HW cvt
__device__ __forceinline__ void dequant16(uint4 q, float4& o0, float4& o1,
                                          float4& o2, float4& o3) {
    vfloat2 f0 = __builtin_amdgcn_cvt_pk_f32_fp8(q.x, false);
    vfloat2 f1 = __builtin_amdgcn_cvt_pk_f32_fp8(q.x, true);
    vfloat2 f2 = __builtin_amdgcn_cvt_pk_f32_fp8(q.y, false);
    vfloat2 f3 = __builtin_amdgcn_cvt_pk_f32_fp8(q.y, true);
    vfloat2 f4 = __builtin_amdgcn_cvt_pk_f32_fp8(q.z, false);
    vfloat2 f5 = __builtin_amdgcn_cvt_pk_f32_fp8(q.z, true);
    vfloat2 f6 = __builtin_amdgcn_cvt_pk_f32_fp8(q.w, false);
    vfloat2 f7 = __builtin_amdgcn_cvt_pk_f32_fp8(q.w, true);
    o0 = make_float4(f0.x, f0.y, f1.x, f1.y);
    o1 = make_float4(f2.x, f2.y, f3.x, f3.y);
    o2 = make_float4(f4.x, f4.y, f5.x, f5.y);
    o3 = make_float4(f6.x, f6.y, f7.x, f7.y);
}

__device__ __forceinline__ float dot4(float4 a, float4 b) {
    return a.x * b.x + a.y * b.y + a.z * b.z + a.w * b.w;
}

// Pre-pass: fp32 table -> fp8 e4m3 table (2 MB, L2-resident) fused with the
// exact-fp32 L2-norm sum (the only full streaming read of the fp32 table).
// 8192 waves, 2 rows each (short dependence chains, high parallelism).
__global__ __launch_bounds__(256) void convert_kernel(const float* __restrict__ embed,
                                                      unsigned short* __restrict__ tab,
                                                      float* __restrict__ partial) {
    __shared__ float red[4];
    const int wave = threadIdx.x >> 6;
    const int lane = threadIdx.x & 63;
    const int gw   = blockIdx.x * 4 + wave;           // 0..8191
    float acc = 0.f;
    #pragma unroll
    for (int r = 0; r < 2; ++r) {
        const int row = gw * 2 + r;
        const float2* rr = (const float2*)(embed + (size_t)row * D_DIM);
        float2 v = rr[lane];                          // elems 2*lane, 2*lane+1
        acc += sqrtf(wave_reduce_sum(v.x * v.x + v.y * v.y));  // exact fp32 norm
        unsigned pk = (unsigned)__builtin_amdgcn_cvt_pk_fp8_f32(v.x, v.y, 0, false);
        tab[(size_t)row * 64 + lane] = (unsigned short)pk;
    }
    if (lane == 0) red[wave] = acc * (L2_REG_F / (float)B_SZ); // pre-scaled
    __syncthreads();
    if (threadIdx.x == 0)
        partial[blockIdx.x] = red[0] + red[1] + red[2] + red[3];
}

// Main: one wave per anchor, everything from the 2 MB L2-resident fp8 table.
// 8 lanes cooperate per negative row (g=lane>>3 row, c=lane&7 16B chunk);
// all 8 gather loads issued up-front for MLP. No LDS staging, no syncthreads
// in the hot path: each lane directly loads its own 16B chunk of a and p.
__global__ __launch_bounds__(256) void npair_kernel(const unsigned short* __restrict__ tab,
                                                    const int* __restrict__ anc_ind,
                                                    const int* __restrict__ pos_ind,
                                                    const int* __restrict__ neg_ind,
                                                    float* __restrict__ partial) {
    __shared__ float red[4];
    const int wave = threadIdx.x >> 6;
    const int lane = threadIdx.x & 63;
    const int i    = blockIdx.x * 4 + wave;           // anchor id 0..8191
    const int g = lane >> 3;   // row-in-pass 0..7
    const int c = lane & 7;    // 16B chunk 0..7 within a 128B row

    const int ai = anc_ind[i];
    const int pi = pos_ind[i];
    const int nid_all = neg_ind[(size_t)i * K_SZ + lane];  // coalesced 256B

    // issue a/p chunk loads immediately (2 lines each, L2-resident)
    uint4 ua4 = ((const uint4*)(tab + (size_t)ai * 64))[c];
    uint4 up4 = ((const uint4*)(tab + (size_t)pi * 64))[c];

    // pre-shuffle all 8 row indices (pass p covers negatives p*8 + g)
    int nidx[8];
    #pragma unroll
    for (int p = 0; p < 8; ++p)
        nidx[p] = __shfl(nid_all, p * 8 + g, 64);

    // issue all 8 independent gather loads (16 lines per instruction)
    uint4 q[8];
    #pragma unroll
    for (int p = 0; p < 8; ++p)
        q[p] = ((const uint4*)(tab + (size_t)nidx[p] * 64))[c];

    // dequant this lane's a chunk (elems c*16 .. c*16+15), reused for all rows
    float4 A0, A1, A2, A3;
    dequant16(ua4, A0, A1, A2, A3);

    // a.p: chunk dot then reduce across c (xor 1,2,4)
    float4 P0, P1, P2, P3;
    dequant16(up4, P0, P1, P2, P3);
    float ap = dot4(A0, P0) + dot4(A1, P1) + dot4(A2, P2) + dot4(A3, P3);
    ap += __shfl_xor(ap, 1, 64);
    ap += __shfl_xor(ap, 2, 64);
    ap += __shfl_xor(ap, 4, 64);

    float inner = 0.f;
    #pragma unroll
    for (int p = 0; p < 8; ++p) {
        float4 N0, N1, N2, N3;
        dequant16(q[p], N0, N1, N2, N3);
        float s = dot4(A0, N0) + dot4(A1, N1) + dot4(A2, N2) + dot4(A3, N3);
        // reduce the 8 chunk-lanes (xor 1,2,4) -> full dot of row p*8+g
        s += __shfl_xor(s, 1, 64);
        s += __shfl_xor(s, 2, 64);
        s += __shfl_xor(s, 4, 64);
        if (c == p) inner = s;   // lane l keeps negative (l&7)*8 + (l>>3)
    }
    inner -= ap;                 // permutation of the 64 inners: LSE-invariant

    float m  = wave_reduce_max(inner);
    float se = wave_reduce_sum(__expf(inner - m));
    float lse = m + __logf(se);
    float per = (lse > 0.f) ? lse + log1pf(__expf(-lse)) : log1pf(__expf(lse));

    if (lane == 0) red[wave] = per * (1.0f / (float)A_SZ);    // pre-scaled
    __syncthreads();
    if (threadIdx.x == 0)
        partial[blockIdx.x] = red[0] + red[1] + red[2] + red[3];
}

// ---- fp32 fallback (used only if ws_size can't hold the fp8 table) ----
__global__ __launch_bounds__(256) void f32_kernel(const float* __restrict__ embed,
                                                  const int* __restrict__ anc_ind,
                                                  const int* __restrict__ pos_ind,
                                                  const int* __restrict__ neg_ind,
                                                  float* __restrict__ partial) {
    __shared__ __align__(16) float a_lds[4][D_DIM];
    __shared__ float red[4];
    const int wave = threadIdx.x >> 6;
    const int lane = threadIdx.x & 63;
    const int gw   = blockIdx.x * 4 + wave;

    float acc_l2 = 0.f;
    #pragma unroll
    for (int r = 0; r < 2; ++r) {
        const int row = gw * 2 + r;
        const float2* rr = (const float2*)(embed + (size_t)row * D_DIM);
        float2 v = rr[lane];
        acc_l2 += sqrtf(wave_reduce_sum(v.x * v.x + v.y * v.y));
    }
    const int i  = gw;
    const int ai = anc_ind[i];
    const int pi = pos_ind[i];
    const int ni = neg_ind[(size_t)i * K_SZ + lane];
    const float2* ar = (const float2*)(embed + (size_t)ai * D_DIM);
    const float2* pr = (const float2*)(embed + (size_t)pi * D_DIM);
    float2 a2 = ar[lane];
    float2 p2 = pr[lane];
    a_lds[wave][2 * lane]     = a2.x;
    a_lds[wave][2 * lane + 1] = a2.y;
    float ap = wave_reduce_sum(a2.x * p2.x + a2.y * p2.y);
    const float4* nr = (const float4*)(embed + (size_t)ni * D_DIM);
    const float4* al = (const float4*)a_lds[wave];
    float s0 = 0.f, s1 = 0.f, s2 = 0.f, s3 = 0.f;
    #pragma unroll
    for (int j = 0; j < D_DIM / 4; j += 4) {
        float4 n0 = nr[j], n1 = nr[j + 1], n2 = nr[j + 2], n3 = nr[j + 3];
        float4 a0 = al[j], a1 = al[j + 1], a2v = al[j + 2], a3 = al[j + 3];
        s0 += dot4(a0, n0); s1 += dot4(a1, n1);
        s2 += dot4(a2v, n2); s3 += dot4(a3, n3);
    }
    float inner = (s0 + s1) + (s2 + s3) - ap;
    float m  = wave_reduce_max(inner);
    float se = wave_reduce_sum(__expf(inner - m));
    float lse = m + __logf(se);
    float per = (lse > 0.f) ? lse + log1pf(__expf(-lse)) : log1pf(__expf(lse));
    float combined = per * (1.0f / (float)A_SZ) + acc_l2 * (L2_REG_F / (float)B_SZ);
    if (lane == 0) red[wave] = combined;
    __syncthreads();
    if (threadIdx.x == 0)
        partial[blockIdx.x] = red[0] + red[1] + red[2] + red[3];
}

__global__ __launch_bounds__(256) void finalize_kernel(const float* __restrict__ partial,
                                                       int n, float* __restrict__ out) {
    __shared__ float red[4];
    const int wave = threadIdx.x >> 6;
    const int lane = threadIdx.x & 63;
    float v = 0.f;
    for (int j = threadIdx.x; j < n; j += 256) v += partial[j];
    v = wave_reduce_sum(v);
    if (lane == 0) red[wave] = v;
    __syncthreads();
    if (threadIdx.x == 0)
        out[0] = red[0] + red[1] + red[2] + red[3];
}

extern "C" void kernel_launch(void* const* d_in, const int* in_sizes, int n_in,
                              void* d_out, int out_size, void* d_ws, size_t ws_size,
                              hipStream_t stream) {
    const float* embed = (const float*)d_in[0];
    const int*   anc   = (const int*)d_in[1];
    const int*   pos   = (const int*)d_in[2];
    const int*   neg   = (const int*)d_in[3];
    float* out = (float*)d_out;

    const size_t tab_bytes = (size_t)B_SZ * D_DIM; // 2 MB fp8
    const size_t need = tab_bytes + (CONV_BLK + NBLK) * sizeof(float);

    if (ws_size >= need) {
        unsigned short* tab = (unsigned short*)d_ws;
        float* partial = (float*)((char*)d_ws + tab_bytes); // [conv | npair]
        convert_kernel<<<CONV_BLK, 256, 0, stream>>>(embed, tab, partial);
        npair_kernel<<<NBLK, 256, 0, stream>>>(tab, anc, pos, neg, partial + CONV_BLK);
        finalize_kernel<<<1, 256, 0, stream>>>(partial, CONV_BLK + NBLK, out);
    } else {
        float* partial = (float*)d_ws;
        f32_kernel<<<NBLK, 256, 0, stream>>>(embed, anc, pos, neg, partial);
        finalize_kernel<<<1, 256, 0, stream>>>(partial, NBLK, out);
    }
}